// Round 2
// baseline (2271.145 us; speedup 1.0000x reference)
//
#include <hip/hip_runtime.h>

// x: [T=8, B=16, Cin=64, H=64, W=64] fp32
// W: [Cout=128, Cin=64, 3, 3] fp32
// out: spikes [T, B, Cout, H, W] fp32 (0.0 / 1.0)
//
// Precision strategy: the output is Heaviside(v - 1). The harness reference
// (ref=np) is precision-neutral (fp64); fp32 conv reordering flips hundreds of
// near-threshold decisions (absmax 1.0). So all accumulation + LIF state is
// fp64: reorder noise ~1e-15 => expected flips ~1e-4 over 536M decisions.
#define TT 8
#define BB 16
#define CIN 64
#define COUT 128
#define HH 64
#define WW 64

#define TILE_H 4
#define TILE_W 16
#define XS_H (TILE_H + 2)                 // 6
#define XS_W (TILE_W + 2)                 // 18
#define XS_ROW (XS_H * XS_W)              // 108 doubles per ci
#define XS_N (CIN * XS_ROW)               // 6912 doubles = 55.3 KB

// Block: 256 threads = 16 cout-groups (8 co each) x 16 pixel columns.
// Each thread: 8 co x 4 rows = 32 outputs; v[32] (double) in regs across t.
// Grid: (64/16=4, 64/4=16, B=16) = 1024 blocks.
__global__ __launch_bounds__(256, 2)
void convlif_f64(const float* __restrict__ x, const float* __restrict__ Wt,
                 float* __restrict__ out) {
    __shared__ double xs[XS_N];

    const int tid = threadIdx.x;
    const int pt = tid & 15;        // pixel column 0..15
    const int cg = tid >> 4;        // cout group 0..15
    const int w0 = blockIdx.x * TILE_W;
    const int h0 = blockIdx.y * TILE_H;
    const int b = blockIdx.z;
    const int co_base = cg * 8;

    double v[32];
#pragma unroll
    for (int i = 0; i < 32; ++i) v[i] = 0.0;

    for (int t = 0; t < TT; ++t) {
        __syncthreads();  // protect xs from previous iteration's readers
        // ---- stage x tile (zero halo) into LDS as double ----
        const float* xb = x + (size_t)(t * BB + b) * (CIN * HH * WW);
        for (int idx = tid; idx < XS_N; idx += 256) {
            int ci = idx / XS_ROW;
            int rem = idx - ci * XS_ROW;
            int hh = rem / XS_W;
            int ww2 = rem - hh * XS_W;
            int gh = h0 - 1 + hh;
            int gw = w0 - 1 + ww2;
            double val = 0.0;
            if (gh >= 0 && gh < HH && gw >= 0 && gw < WW)
                val = (double)xb[ci * (HH * WW) + gh * WW + gw];
            xs[idx] = val;
        }
        __syncthreads();

        // ---- conv accumulate in fp64 ----
        double acc[32];
#pragma unroll
        for (int i = 0; i < 32; ++i) acc[i] = 0.0;

        for (int ci = 0; ci < CIN; ++ci) {
            const float* wr = Wt + (size_t)co_base * (CIN * 9) + ci * 9;
            const double* xr = xs + ci * XS_ROW;
#pragma unroll
            for (int kh = 0; kh < 3; ++kh) {
#pragma unroll
                for (int kw = 0; kw < 3; ++kw) {
                    double wv[8];
#pragma unroll
                    for (int i = 0; i < 8; ++i)
                        wv[i] = (double)wr[i * (CIN * 9) + kh * 3 + kw];
                    double xv[4];
#pragma unroll
                    for (int j = 0; j < 4; ++j)
                        xv[j] = xr[(j + kh) * XS_W + pt + kw];
#pragma unroll
                    for (int i = 0; i < 8; ++i) {
#pragma unroll
                        for (int j = 0; j < 4; ++j)
                            acc[i * 4 + j] = fma(wv[i], xv[j], acc[i * 4 + j]);
                    }
                }
            }
        }

        // ---- LIF update + spike store (all fp64, exact *0.5) ----
        float* ob = out + (size_t)(t * BB + b) * (COUT * HH * WW);
#pragma unroll
        for (int i = 0; i < 8; ++i) {
#pragma unroll
            for (int j = 0; j < 4; ++j) {
                int k = i * 4 + j;
                double vv = v[k] + (acc[k] - v[k]) * 0.5;  // v += (z - v)/tau
                bool s = (vv >= 1.0);
                ob[(size_t)(co_base + i) * (HH * WW) + (h0 + j) * WW + (w0 + pt)]
                    = s ? 1.0f : 0.0f;
                v[k] = s ? 0.0 : vv;
            }
        }
    }
}

extern "C" void kernel_launch(void* const* d_in, const int* in_sizes, int n_in,
                              void* d_out, int out_size, void* d_ws, size_t ws_size,
                              hipStream_t stream) {
    const float* x = (const float*)d_in[0];
    const float* Wt = (const float*)d_in[1];
    float* out = (float*)d_out;
    dim3 grid(WW / TILE_W, HH / TILE_H, BB);
    convlif_f64<<<grid, 256, 0, stream>>>(x, Wt, out);
}